// Round 9
// baseline (198.500 us; speedup 1.0000x reference)
//
#include <hip/hip_runtime.h>

typedef __bf16 bf16;
typedef __bf16 bf16x4 __attribute__((ext_vector_type(4)));
typedef __bf16 bf16x8 __attribute__((ext_vector_type(8)));
typedef float f32x4 __attribute__((ext_vector_type(4)));
typedef float f32x16 __attribute__((ext_vector_type(16)));

#define DIMD 1024
#define NHEAD 16
#define HDIM 64
#define BATCH 2
#define SEQ 2048
#define MTOT (BATCH*SEQ)   // 4096

#define EXP2F(x) __builtin_amdgcn_exp2f(x)

// ---- memory plan (ws_size ~= 256 MiB per fillBufferAligned WRITE_SIZE) ----
// d_out: [0,8MB) Qb bf16 (pre-scaled 0.125*log2e); [8,16MB) Kb
// d_ws:  [0,8MB)   xb bf16 -> dead after QKV GEMM, then Ob (combine output)
//        [8,16MB)  Vt bf16 -> dead after attn, then wprojb bf16 (2MB)
//        [16,22MB) wqkvb bf16
//        [32,64MB) ph f32 partial O [half][bh*SEQ+s][64]
//        [64,65MB) ml f32 partial (m,l) [half][bh*SEQ+s][2]
#define OFF_XB (0ull)
#define OFF_OB (0ull)
#define OFF_VT (8ull<<20)
#define OFF_WP (8ull<<20)
#define OFF_WQ (16ull<<20)
#define OFF_PH (32ull<<20)
#define OFF_ML (64ull<<20)

__device__ __forceinline__ void g2l16(const void* g, void* l) {
  __builtin_amdgcn_global_load_lds(
      (const __attribute__((address_space(1))) void*)g,
      (__attribute__((address_space(3))) void*)l,
      16, 0, 0);
}

// ---------------- fp32 -> bf16 conversion ----------------
__global__ __launch_bounds__(256) void cvt_kernel(const float* __restrict__ in,
                                                  bf16* __restrict__ out, int n4) {
  int i = blockIdx.x * blockDim.x + threadIdx.x;
  if (i < n4) {
    float4 v = ((const float4*)in)[i];
    bf16x4 o = { (bf16)v.x, (bf16)v.y, (bf16)v.z, (bf16)v.w };
    ((bf16x4*)out)[i] = o;
  }
}

// fused: x (1M float4) + w_qkv (768K float4) in one launch
__global__ __launch_bounds__(256) void cvt2_kernel(
    const float* __restrict__ x, const float* __restrict__ wq,
    bf16* __restrict__ xb, bf16* __restrict__ wqb) {
  const int NX = MTOT * DIMD / 4;
  const int NW = 3 * DIMD * DIMD / 4;
  int i = blockIdx.x * blockDim.x + threadIdx.x;
  if (i < NX) {
    float4 v = ((const float4*)x)[i];
    bf16x4 o = { (bf16)v.x, (bf16)v.y, (bf16)v.z, (bf16)v.w };
    ((bf16x4*)xb)[i] = o;
  } else if (i < NX + NW) {
    int j = i - NX;
    float4 v = ((const float4*)wq)[j];
    bf16x4 o = { (bf16)v.x, (bf16)v.y, (bf16)v.z, (bf16)v.w };
    ((bf16x4*)wqb)[j] = o;
  }
}

// ---------------- QKV GEMM v2: BOTH operands async via g2l16 (R8 proven) ----
__global__ __launch_bounds__(256, 3) void gemm_qkv(
    const bf16* __restrict__ A, const bf16* __restrict__ Bt,
    const float* __restrict__ bias,
    bf16* __restrict__ Qb, bf16* __restrict__ Kb, bf16* __restrict__ Vt)
{
  __shared__ bf16 lA[2][128 * 32];
  __shared__ bf16 lB[2][128 * 32];
  const int tid = threadIdx.x;
  const int wave = tid >> 6, lane = tid & 63;
  const int l15 = lane & 15, quad = lane >> 4;
  const int wm = wave >> 1, wn = wave & 1;
  const int tm = blockIdx.y * 128, tn = blockIdx.x * 128;

  f32x4 acc[4][4] = {};

  const int srow = tid >> 2, sch = (tid & 3) * 8;
  const bf16* ga = &A[(size_t)(tm + srow) * DIMD + sch];
  const bf16* gb = &Bt[(size_t)(tn + srow) * DIMD + sch];

  g2l16(ga,                     &lA[0][wave * 512]);
  g2l16(ga + (size_t)64 * DIMD, &lA[0][2048 + wave * 512]);
  g2l16(gb,                     &lB[0][wave * 512]);
  g2l16(gb + (size_t)64 * DIMD, &lB[0][2048 + wave * 512]);

  for (int kt = 0; kt < 32; kt++) {
    __syncthreads();

    if (kt < 31) {
      const int kn = (kt + 1) * 32;
      bf16* nA = lA[(kt + 1) & 1];
      bf16* nB = lB[(kt + 1) & 1];
      g2l16(ga + kn,                     &nA[wave * 512]);
      g2l16(ga + kn + (size_t)64 * DIMD, &nA[2048 + wave * 512]);
      g2l16(gb + kn,                     &nB[wave * 512]);
      g2l16(gb + kn + (size_t)64 * DIMD, &nB[2048 + wave * 512]);
    }

    const bf16* sA = lA[kt & 1];
    const bf16* sB = lB[kt & 1];
    bf16x8 af[4], bfr[4];
#pragma unroll
    for (int i = 0; i < 4; i++)
      af[i] = *(const bf16x8*)&sA[(wm * 64 + i * 16 + l15) * 32 + quad * 8];
#pragma unroll
    for (int i = 0; i < 4; i++)
      bfr[i] = *(const bf16x8*)&sB[(wn * 64 + i * 16 + l15) * 32 + quad * 8];
#pragma unroll
    for (int i = 0; i < 4; i++)
#pragma unroll
      for (int j = 0; j < 4; j++)
        acc[i][j] = __builtin_amdgcn_mfma_f32_16x16x32_bf16(af[i], bfr[j], acc[i][j], 0, 0, 0);
  }

  const int sel = tn >> 10;  // 0=Q 1=K 2=V
#pragma unroll
  for (int j = 0; j < 4; j++) {
    const int n = tn + wn * 64 + j * 16 + l15;
    const float bv = bias[n];
    const int d = n & 1023, h = d >> 6, hd = d & 63;
#pragma unroll
    for (int i = 0; i < 4; i++) {
      const int mbase = tm + wm * 64 + i * 16 + quad * 4;
      const int b = mbase >> 11, s0 = mbase & 2047;
      const int bh = b * NHEAD + h;
      if (sel == 2) {
        bf16x4 vv = { (bf16)(acc[i][j][0] + bv), (bf16)(acc[i][j][1] + bv),
                      (bf16)(acc[i][j][2] + bv), (bf16)(acc[i][j][3] + bv) };
        *(bf16x4*)&Vt[((size_t)bh * HDIM + hd) * SEQ + s0] = vv;
      } else {
#pragma unroll
        for (int r = 0; r < 4; r++) {
          float v = acc[i][j][r] + bv;
          if (sel == 0)
            Qb[((size_t)bh * SEQ + s0 + r) * HDIM + hd] = (bf16)(v * 0.18033688f); // 0.125*log2e
          else
            Kb[((size_t)bh * SEQ + s0 + r) * HDIM + hd] = (bf16)v;
        }
      }
    }
  }
}

// ---------------- proj GEMM v2 (g2l16 both — R8 proven) ---------------------
__global__ __launch_bounds__(256, 2) void gemm_proj(
    const bf16* __restrict__ A, const bf16* __restrict__ Bt,
    const float* __restrict__ bias, float* __restrict__ out)
{
  __shared__ bf16 lA[2][64 * 32];
  __shared__ bf16 lB[2][128 * 32];
  const int tid = threadIdx.x;
  const int wave = tid >> 6, lane = tid & 63;
  const int l15 = lane & 15, quad = lane >> 4;
  const int tm = blockIdx.y * 64, tn = blockIdx.x * 128;

  f32x4 acc[4][2] = {};

  const int srow = tid >> 2, sch = (tid & 3) * 8;
  const bf16* ga = &A[(size_t)(tm + srow) * DIMD + sch];
  const bf16* gb = &Bt[(size_t)(tn + srow) * DIMD + sch];

  g2l16(ga,                     &lA[0][wave * 512]);
  g2l16(gb,                     &lB[0][wave * 512]);
  g2l16(gb + (size_t)64 * DIMD, &lB[0][2048 + wave * 512]);

  for (int kt = 0; kt < 32; kt++) {
    __syncthreads();

    if (kt < 31) {
      const int kn = (kt + 1) * 32;
      bf16* nA = lA[(kt + 1) & 1];
      bf16* nB = lB[(kt + 1) & 1];
      g2l16(ga + kn,                     &nA[wave * 512]);
      g2l16(gb + kn,                     &nB[wave * 512]);
      g2l16(gb + kn + (size_t)64 * DIMD, &nB[2048 + wave * 512]);
    }

    const bf16* sA = lA[kt & 1];
    const bf16* sB = lB[kt & 1];
    bf16x8 af[4], bfr[2];
#pragma unroll
    for (int i = 0; i < 4; i++)
      af[i] = *(const bf16x8*)&sA[(i * 16 + l15) * 32 + quad * 8];
#pragma unroll
    for (int j = 0; j < 2; j++)
      bfr[j] = *(const bf16x8*)&sB[(wave * 32 + j * 16 + l15) * 32 + quad * 8];
#pragma unroll
    for (int i = 0; i < 4; i++)
#pragma unroll
      for (int j = 0; j < 2; j++)
        acc[i][j] = __builtin_amdgcn_mfma_f32_16x16x32_bf16(af[i], bfr[j], acc[i][j], 0, 0, 0);
  }

#pragma unroll
  for (int j = 0; j < 2; j++) {
    const int n = tn + wave * 32 + j * 16 + l15;
    const float bv = bias[n];
#pragma unroll
    for (int i = 0; i < 4; i++) {
      const int mbase = tm + i * 16 + quad * 4;
#pragma unroll
      for (int r = 0; r < 4; r++)
        out[(size_t)(mbase + r) * DIMD + n] = acc[i][j][r] + bv;
    }
  }
}

// ---------------- flash attention v15: 2-way split-K ------------------------
// v10 body unchanged (VGPR 64, conflicts 0 — no spill risk). Grid doubles:
// each block covers KV rows [half*1024, half*1024+1024) -> 1024 blocks ->
// 4 blocks/CU (LDS 36.9KB) -> 4 waves/SIMD, up from the work-capped 2.
// Theory: pipes time-shared serially (MFMA23+VALU41+DS25 ~= 90%); more
// independent blocks/CU lets block A's MFMA overlap block B's softmax ->
// wall approaches the VALU pipe (~41%) instead of the sum.
// Epilogue: raw partials (o f32, m, l) -> combine kernel merges halves.
#define LSTR 72
__global__ __launch_bounds__(256, 2) void attn_kernel(
    const bf16* __restrict__ Qb, const bf16* __restrict__ Kb,
    const bf16* __restrict__ Vt, float* __restrict__ ph,
    float* __restrict__ ml)
{
  __shared__ bf16 lKV[2][2][64 * LSTR];   // [buf][K=0/V=1]

  const int tid = threadIdx.x;
  const int wave = tid >> 6, lane = tid & 63;
  const int l31 = lane & 31, h = lane >> 5;
  const int bid = blockIdx.x;             // 1024 blocks
  const int xcd = bid & 7, grp = bid >> 3;
  const int bh = xcd + 8 * (grp & 3);
  const int qt = (grp >> 2) & 15;
  const int half = grp >> 6;              // KV half: rows [half*1024, +1024)

  const int qrow = qt * 128 + wave * 32 + l31;
  const bf16* qp = Qb + ((size_t)bh * SEQ + qrow) * HDIM + h * 8;
  bf16x8 qf[4];
#pragma unroll
  for (int c = 0; c < 4; c++) qf[c] = *(const bf16x8*)(qp + c * 16);

  const int srow = tid >> 3;            // 0..31
  const int sch = (tid & 7) * 8;        // bf16 elem offset in 64
  const bf16* kg = Kb + ((size_t)bh * SEQ + half * 1024 + srow) * HDIM + sch;
  const bf16* vg = Vt + ((size_t)bh * HDIM + srow) * SEQ + half * 1024 + sch;

  uint4 kr0 = *(const uint4*)(kg);
  uint4 kr1 = *(const uint4*)(kg + 32 * HDIM);
  uint4 vr0 = *(const uint4*)(vg);
  uint4 vr1 = *(const uint4*)(vg + 32 * SEQ);

  bf16x8 pf[4];   // packed P(t-1)

  f32x16 o0 = {}, o1 = {};
  float mrow = -1e30f, lrow = 0.f;

  for (int kt = 0; kt < 16; kt++) {     // 1024 KV rows per block
    bf16* sK = lKV[kt & 1][0];
    bf16* sV = lKV[kt & 1][1];
    *(uint4*)&sK[srow * LSTR + sch]        = kr0;
    *(uint4*)&sK[(32 + srow) * LSTR + sch] = kr1;
    *(uint4*)&sV[srow * LSTR + sch]        = vr0;
    *(uint4*)&sV[(32 + srow) * LSTR + sch] = vr1;
    __syncthreads();

    const int ktn = (kt + 1) & 15;
    kr0 = *(const uint4*)(kg + (size_t)ktn * 64 * HDIM);
    kr1 = *(const uint4*)(kg + (size_t)ktn * 64 * HDIM + 32 * HDIM);
    vr0 = *(const uint4*)(vg + ktn * 64);
    vr1 = *(const uint4*)(vg + ktn * 64 + 32 * SEQ);

    // S^T(t) = K Q^T
    f32x16 s0 = {}, s1 = {};
#pragma unroll
    for (int c = 0; c < 4; c++) {
      bf16x8 k0 = *(const bf16x8*)&sK[l31 * LSTR + c * 16 + h * 8];
      bf16x8 k1 = *(const bf16x8*)&sK[(32 + l31) * LSTR + c * 16 + h * 8];
      s0 = __builtin_amdgcn_mfma_f32_32x32x16_bf16(k0, qf[c], s0, 0, 0, 0);
      s1 = __builtin_amdgcn_mfma_f32_32x32x16_bf16(k1, qf[c], s1, 0, 0, 0);
    }

    // PV(t-1): P in pf regs, V(t-1) in the OTHER KV buffer.
    if (kt > 0) {
      const bf16* pV = lKV[(kt + 1) & 1][1];
#pragma unroll
      for (int c = 0; c < 4; c++) {
        bf16x8 v0 = *(const bf16x8*)&pV[l31 * LSTR + c * 16 + h * 8];
        bf16x8 v1 = *(const bf16x8*)&pV[(32 + l31) * LSTR + c * 16 + h * 8];
        o0 = __builtin_amdgcn_mfma_f32_32x32x16_bf16(v0, pf[c], o0, 0, 0, 0);
        o1 = __builtin_amdgcn_mfma_f32_32x32x16_bf16(v1, pf[c], o1, 0, 0, 0);
      }
    }

    // softmax(t)
    float mx = -1e30f;
#pragma unroll
    for (int r = 0; r < 16; r++) { mx = fmaxf(mx, s0[r]); mx = fmaxf(mx, s1[r]); }
    mx = fmaxf(mx, __shfl_xor(mx, 32, 64));
    const float nm = fmaxf(mrow, mx);
    const float alpha = EXP2F(mrow - nm);
    mrow = nm;

    float rs = 0.f;
#pragma unroll
    for (int r = 0; r < 16; r++) {
      const float p0 = EXP2F(s0[r] - nm);
      const float p1 = EXP2F(s1[r] - nm);
      s0[r] = p0; s1[r] = p1;
      rs += p0 + p1;
    }
    rs += __shfl_xor(rs, 32, 64);
    lrow = lrow * alpha + rs;

#pragma unroll
    for (int r = 0; r < 16; r++) { o0[r] *= alpha; o1[r] *= alpha; }

    // pack P(t) -> pf regs via half-exchange
#pragma unroll
    for (int g = 0; g < 2; g++) {
      const f32x16& sg = (g == 0) ? s0 : s1;
#pragma unroll
      for (int cp = 0; cp < 2; cp++) {
        bf16x4 pk0 = { (bf16)sg[8 * cp + 0], (bf16)sg[8 * cp + 1],
                       (bf16)sg[8 * cp + 2], (bf16)sg[8 * cp + 3] };
        bf16x4 pk1 = { (bf16)sg[8 * cp + 4], (bf16)sg[8 * cp + 5],
                       (bf16)sg[8 * cp + 6], (bf16)sg[8 * cp + 7] };
        uint2 w0 = *(uint2*)&pk0;
        uint2 w1 = *(uint2*)&pk1;
        unsigned send0 = h ? w0.x : w1.x;
        unsigned send1 = h ? w0.y : w1.y;
        unsigned recv0 = __shfl_xor(send0, 32, 64);
        unsigned recv1 = __shfl_xor(send1, 32, 64);
        union { unsigned u[4]; bf16x8 v; } f;
        f.u[0] = h ? recv0 : w0.x;
        f.u[1] = h ? recv1 : w0.y;
        f.u[2] = h ? w1.x : recv0;
        f.u[3] = h ? w1.y : recv1;
        pf[2 * g + cp] = f.v;
      }
    }
  }

  // drain: PV(15) from buf[15&1 = 1]
  {
    const bf16* pV = lKV[1][1];
#pragma unroll
    for (int c = 0; c < 4; c++) {
      bf16x8 v0 = *(const bf16x8*)&pV[l31 * LSTR + c * 16 + h * 8];
      bf16x8 v1 = *(const bf16x8*)&pV[(32 + l31) * LSTR + c * 16 + h * 8];
      o0 = __builtin_amdgcn_mfma_f32_32x32x16_bf16(v0, pf[c], o0, 0, 0, 0);
      o1 = __builtin_amdgcn_mfma_f32_32x32x16_bf16(v1, pf[c], o1, 0, 0, 0);
    }
  }

  // epilogue: raw partials (no division) — f32 to protect absmax
  const size_t prow = (size_t)(half * 32 + bh) * SEQ + qrow;
  float* pb = ph + prow * HDIM;
#pragma unroll
  for (int g = 0; g < 4; g++) {
    float4 fa = { o0[4*g], o0[4*g+1], o0[4*g+2], o0[4*g+3] };
    float4 fb = { o1[4*g], o1[4*g+1], o1[4*g+2], o1[4*g+3] };
    *(float4*)&pb[g * 8 + h * 4]      = fa;
    *(float4*)&pb[32 + g * 8 + h * 4] = fb;
  }
  if (h == 0) {
    float2 mlv = { mrow, lrow };
    *(float2*)&ml[prow * 2] = mlv;
  }
}

// ---------------- split-K combine: Ob = merge(half0, half1) -----------------
// 16 rows/block; 16 threads/row cover 64 cols as float4 (coalesced 256B).
__global__ __launch_bounds__(256) void combine_kernel(
    const float* __restrict__ ph, const float* __restrict__ ml,
    bf16* __restrict__ Ob)
{
  const int tid = threadIdx.x;
  const int row = blockIdx.x * 16 + (tid >> 4);   // 0..65535 = bh*SEQ + s
  const int c = (tid & 15) * 4;
  const size_t r0 = (size_t)row, r1 = (size_t)(32 * SEQ) * NHEAD / NHEAD * 0 + 65536 + row;

  float2 ml0 = *(const float2*)&ml[r0 * 2];
  float2 ml1 = *(const float2*)&ml[r1 * 2];
  const float ms = fmaxf(ml0.x, ml1.x);
  const float w0 = EXP2F(ml0.x - ms), w1 = EXP2F(ml1.x - ms);
  const float inv = 1.f / (ml0.y * w0 + ml1.y * w1);

  float4 a = *(const float4*)&ph[r0 * HDIM + c];
  float4 b = *(const float4*)&ph[r1 * HDIM + c];

  const int bh = row >> 11, s = row & 2047;
  const int bb = bh >> 4, head = bh & 15;
  bf16x4 o = { (bf16)((a.x * w0 + b.x * w1) * inv),
               (bf16)((a.y * w0 + b.y * w1) * inv),
               (bf16)((a.z * w0 + b.z * w1) * inv),
               (bf16)((a.w * w0 + b.w * w1) * inv) };
  *(bf16x4*)&Ob[((size_t)bb * SEQ + s) * DIMD + head * HDIM + c] = o;
}

extern "C" void kernel_launch(void* const* d_in, const int* in_sizes, int n_in,
                              void* d_out, int out_size, void* d_ws, size_t ws_size,
                              hipStream_t stream) {
  const float* x      = (const float*)d_in[0];
  const float* w_qkv  = (const float*)d_in[1];
  const float* b_qkv  = (const float*)d_in[2];
  const float* w_proj = (const float*)d_in[3];
  const float* b_proj = (const float*)d_in[4];
  float* out = (float*)d_out;
  char* ws = (char*)d_ws;

  bf16* Qb = (bf16*)d_out;
  bf16* Kb = (bf16*)d_out + (size_t)MTOT * DIMD;
  bf16* xb     = (bf16*)(ws + OFF_XB);
  bf16* Ob     = (bf16*)(ws + OFF_OB);   // overlays xb (dead after QKV GEMM)
  bf16* Vt     = (bf16*)(ws + OFF_VT);
  bf16* wprojb = (bf16*)(ws + OFF_WP);   // overlays Vt (dead after attn)
  bf16* wqkvb  = (bf16*)(ws + OFF_WQ);
  float* ph    = (float*)(ws + OFF_PH);
  float* ml    = (float*)(ws + OFF_ML);

  const int NCVT = (MTOT * DIMD / 4) + (3 * DIMD * DIMD / 4);
  cvt2_kernel<<<NCVT / 256, 256, 0, stream>>>(x, w_qkv, xb, wqkvb);
  gemm_qkv<<<dim3(24, 32), 256, 0, stream>>>(xb, wqkvb, b_qkv, Qb, Kb, Vt);
  attn_kernel<<<2 * BATCH * NHEAD * (SEQ / 128), 256, 0, stream>>>(Qb, Kb, Vt, ph, ml);
  combine_kernel<<<(BATCH * NHEAD * SEQ) / 16, 256, 0, stream>>>(ph, ml, Ob);
  cvt_kernel<<<(DIMD * DIMD / 4) / 256, 256, 0, stream>>>(w_proj, wprojb, DIMD * DIMD / 4);
  gemm_proj<<<dim3(8, 64), 256, 0, stream>>>(Ob, wprojb, b_proj, out);
}

// Round 10
// 187.587 us; speedup vs baseline: 1.0582x; 1.0582x over previous
//
#include <hip/hip_runtime.h>

typedef __bf16 bf16;
typedef __bf16 bf16x4 __attribute__((ext_vector_type(4)));
typedef __bf16 bf16x8 __attribute__((ext_vector_type(8)));
typedef float f32x4 __attribute__((ext_vector_type(4)));
typedef float f32x16 __attribute__((ext_vector_type(16)));

#define DIMD 1024
#define NHEAD 16
#define HDIM 64
#define BATCH 2
#define SEQ 2048
#define MTOT (BATCH*SEQ)   // 4096

#define EXP2F(x) __builtin_amdgcn_exp2f(x)

// ---- memory plan (ws_size ~= 256 MiB per fillBufferAligned WRITE_SIZE) ----
// d_out: [0,8MB) Qb bf16 (pre-scaled 0.125*log2e); [8,16MB) Kb
// d_ws:  [0,8MB)   xb bf16 -> dead after QKV GEMM, then Ob
//        [8,16MB)  Vt bf16
//        [16,22MB) wqkvb bf16
//        [24,26MB) wprojb bf16 (own region — no Vt alias, enables 1-launch cvt)
#define OFF_XB (0ull)
#define OFF_OB (0ull)
#define OFF_VT (8ull<<20)
#define OFF_WQ (16ull<<20)
#define OFF_WP (24ull<<20)

__device__ __forceinline__ void g2l16(const void* g, void* l) {
  __builtin_amdgcn_global_load_lds(
      (const __attribute__((address_space(1))) void*)g,
      (__attribute__((address_space(3))) void*)l,
      16, 0, 0);
}

// ---------------- fused fp32 -> bf16 conversion: x + w_qkv + w_proj ---------
// One launch for all three inputs (R8 had w_proj separate only because wprojb
// aliased live Vt; 256MiB ws removes the alias). -1 kernel launch vs R8.
__global__ __launch_bounds__(256) void cvt3_kernel(
    const float* __restrict__ x, const float* __restrict__ wq,
    const float* __restrict__ wp,
    bf16* __restrict__ xb, bf16* __restrict__ wqb, bf16* __restrict__ wpb) {
  const int NX = MTOT * DIMD / 4;
  const int NW = 3 * DIMD * DIMD / 4;
  const int NP = DIMD * DIMD / 4;
  int i = blockIdx.x * blockDim.x + threadIdx.x;
  if (i < NX) {
    float4 v = ((const float4*)x)[i];
    bf16x4 o = { (bf16)v.x, (bf16)v.y, (bf16)v.z, (bf16)v.w };
    ((bf16x4*)xb)[i] = o;
  } else if (i < NX + NW) {
    int j = i - NX;
    float4 v = ((const float4*)wq)[j];
    bf16x4 o = { (bf16)v.x, (bf16)v.y, (bf16)v.z, (bf16)v.w };
    ((bf16x4*)wqb)[j] = o;
  } else if (i < NX + NW + NP) {
    int j = i - NX - NW;
    float4 v = ((const float4*)wp)[j];
    bf16x4 o = { (bf16)v.x, (bf16)v.y, (bf16)v.z, (bf16)v.w };
    ((bf16x4*)wpb)[j] = o;
  }
}

// ---------------- QKV GEMM v2: BOTH operands async via g2l16 (R8 proven) ----
__global__ __launch_bounds__(256, 3) void gemm_qkv(
    const bf16* __restrict__ A, const bf16* __restrict__ Bt,
    const float* __restrict__ bias,
    bf16* __restrict__ Qb, bf16* __restrict__ Kb, bf16* __restrict__ Vt)
{
  __shared__ bf16 lA[2][128 * 32];
  __shared__ bf16 lB[2][128 * 32];
  const int tid = threadIdx.x;
  const int wave = tid >> 6, lane = tid & 63;
  const int l15 = lane & 15, quad = lane >> 4;
  const int wm = wave >> 1, wn = wave & 1;
  const int tm = blockIdx.y * 128, tn = blockIdx.x * 128;

  f32x4 acc[4][4] = {};

  const int srow = tid >> 2, sch = (tid & 3) * 8;
  const bf16* ga = &A[(size_t)(tm + srow) * DIMD + sch];
  const bf16* gb = &Bt[(size_t)(tn + srow) * DIMD + sch];

  g2l16(ga,                     &lA[0][wave * 512]);
  g2l16(ga + (size_t)64 * DIMD, &lA[0][2048 + wave * 512]);
  g2l16(gb,                     &lB[0][wave * 512]);
  g2l16(gb + (size_t)64 * DIMD, &lB[0][2048 + wave * 512]);

  for (int kt = 0; kt < 32; kt++) {
    __syncthreads();   // drains g2l16(kt); separates buf rewrite from t-1 reads

    if (kt < 31) {
      const int kn = (kt + 1) * 32;
      bf16* nA = lA[(kt + 1) & 1];
      bf16* nB = lB[(kt + 1) & 1];
      g2l16(ga + kn,                     &nA[wave * 512]);
      g2l16(ga + kn + (size_t)64 * DIMD, &nA[2048 + wave * 512]);
      g2l16(gb + kn,                     &nB[wave * 512]);
      g2l16(gb + kn + (size_t)64 * DIMD, &nB[2048 + wave * 512]);
    }

    const bf16* sA = lA[kt & 1];
    const bf16* sB = lB[kt & 1];
    bf16x8 af[4], bfr[4];
#pragma unroll
    for (int i = 0; i < 4; i++)
      af[i] = *(const bf16x8*)&sA[(wm * 64 + i * 16 + l15) * 32 + quad * 8];
#pragma unroll
    for (int i = 0; i < 4; i++)
      bfr[i] = *(const bf16x8*)&sB[(wn * 64 + i * 16 + l15) * 32 + quad * 8];
#pragma unroll
    for (int i = 0; i < 4; i++)
#pragma unroll
      for (int j = 0; j < 4; j++)
        acc[i][j] = __builtin_amdgcn_mfma_f32_16x16x32_bf16(af[i], bfr[j], acc[i][j], 0, 0, 0);
  }

  const int sel = tn >> 10;  // 0=Q 1=K 2=V
#pragma unroll
  for (int j = 0; j < 4; j++) {
    const int n = tn + wn * 64 + j * 16 + l15;
    const float bv = bias[n];
    const int d = n & 1023, h = d >> 6, hd = d & 63;
#pragma unroll
    for (int i = 0; i < 4; i++) {
      const int mbase = tm + wm * 64 + i * 16 + quad * 4;
      const int b = mbase >> 11, s0 = mbase & 2047;
      const int bh = b * NHEAD + h;
      if (sel == 2) {
        bf16x4 vv = { (bf16)(acc[i][j][0] + bv), (bf16)(acc[i][j][1] + bv),
                      (bf16)(acc[i][j][2] + bv), (bf16)(acc[i][j][3] + bv) };
        *(bf16x4*)&Vt[((size_t)bh * HDIM + hd) * SEQ + s0] = vv;
      } else {
#pragma unroll
        for (int r = 0; r < 4; r++) {
          float v = acc[i][j][r] + bv;
          if (sel == 0)
            Qb[((size_t)bh * SEQ + s0 + r) * HDIM + hd] = (bf16)(v * 0.18033688f); // 0.125*log2e
          else
            Kb[((size_t)bh * SEQ + s0 + r) * HDIM + hd] = (bf16)v;
        }
      }
    }
  }
}

// ---------------- proj GEMM v2 (g2l16 both — R8 proven) ---------------------
__global__ __launch_bounds__(256, 2) void gemm_proj(
    const bf16* __restrict__ A, const bf16* __restrict__ Bt,
    const float* __restrict__ bias, float* __restrict__ out)
{
  __shared__ bf16 lA[2][64 * 32];
  __shared__ bf16 lB[2][128 * 32];
  const int tid = threadIdx.x;
  const int wave = tid >> 6, lane = tid & 63;
  const int l15 = lane & 15, quad = lane >> 4;
  const int tm = blockIdx.y * 64, tn = blockIdx.x * 128;

  f32x4 acc[4][2] = {};

  const int srow = tid >> 2, sch = (tid & 3) * 8;
  const bf16* ga = &A[(size_t)(tm + srow) * DIMD + sch];
  const bf16* gb = &Bt[(size_t)(tn + srow) * DIMD + sch];

  g2l16(ga,                     &lA[0][wave * 512]);
  g2l16(gb,                     &lB[0][wave * 512]);
  g2l16(gb + (size_t)64 * DIMD, &lB[0][2048 + wave * 512]);

  for (int kt = 0; kt < 32; kt++) {
    __syncthreads();

    if (kt < 31) {
      const int kn = (kt + 1) * 32;
      bf16* nA = lA[(kt + 1) & 1];
      bf16* nB = lB[(kt + 1) & 1];
      g2l16(ga + kn,                     &nA[wave * 512]);
      g2l16(gb + kn,                     &nB[wave * 512]);
      g2l16(gb + kn + (size_t)64 * DIMD, &nB[2048 + wave * 512]);
    }

    const bf16* sA = lA[kt & 1];
    const bf16* sB = lB[kt & 1];
    bf16x8 af[4], bfr[2];
#pragma unroll
    for (int i = 0; i < 4; i++)
      af[i] = *(const bf16x8*)&sA[(i * 16 + l15) * 32 + quad * 8];
#pragma unroll
    for (int j = 0; j < 2; j++)
      bfr[j] = *(const bf16x8*)&sB[(wave * 32 + j * 16 + l15) * 32 + quad * 8];
#pragma unroll
    for (int i = 0; i < 4; i++)
#pragma unroll
      for (int j = 0; j < 2; j++)
        acc[i][j] = __builtin_amdgcn_mfma_f32_16x16x32_bf16(af[i], bfr[j], acc[i][j], 0, 0, 0);
  }

#pragma unroll
  for (int j = 0; j < 2; j++) {
    const int n = tn + wave * 32 + j * 16 + l15;
    const float bv = bias[n];
#pragma unroll
    for (int i = 0; i < 4; i++) {
      const int mbase = tm + i * 16 + quad * 4;
#pragma unroll
      for (int r = 0; r < 4; r++)
        out[(size_t)(mbase + r) * DIMD + n] = acc[i][j][r] + bv;
    }
  }
}

// ---------------- flash attention v10 (best proven: 57.6us, ±4 noise) -------
// Session findings baked in: in-register P (pack + __shfl_xor half-exchange,
// HW-validated), 0 bank conflicts, VGPR 64. Dead ends measured on this
// toolchain: KVBLK=128 (spills at 128 VGPR regardless of waves_per_eu),
// direct-global V fragments (4KB lane stride -> TA-bound), split-K=2 (-5us
// attn but +17us combine plumbing), defer-max/tree-reduce (chain not the
// critical path), 128B-row XOR swizzle (LSTR=72 pad already conflict-free).
#define LSTR 72
__global__ __launch_bounds__(256, 2) void attn_kernel(
    const bf16* __restrict__ Qb, const bf16* __restrict__ Kb,
    const bf16* __restrict__ Vt, bf16* __restrict__ Ob)
{
  __shared__ bf16 lKV[2][2][64 * LSTR];   // [buf][K=0/V=1]

  const int tid = threadIdx.x;
  const int wave = tid >> 6, lane = tid & 63;
  const int l31 = lane & 31, h = lane >> 5;
  const int xcd = blockIdx.x & 7, grp = blockIdx.x >> 3;
  const int bh = xcd + 8 * (grp & 3);
  const int qt = grp >> 2;

  const int qrow = qt * 128 + wave * 32 + l31;
  const bf16* qp = Qb + ((size_t)bh * SEQ + qrow) * HDIM + h * 8;
  bf16x8 qf[4];
#pragma unroll
  for (int c = 0; c < 4; c++) qf[c] = *(const bf16x8*)(qp + c * 16);

  const int srow = tid >> 3;            // 0..31
  const int sch = (tid & 7) * 8;        // bf16 elem offset in 64
  const bf16* kg = Kb + ((size_t)bh * SEQ + srow) * HDIM + sch;
  const bf16* vg = Vt + ((size_t)bh * HDIM + srow) * SEQ + sch;

  uint4 kr0 = *(const uint4*)(kg);
  uint4 kr1 = *(const uint4*)(kg + 32 * HDIM);
  uint4 vr0 = *(const uint4*)(vg);
  uint4 vr1 = *(const uint4*)(vg + 32 * SEQ);

  bf16x8 pf[4];   // packed P(t-1)

  f32x16 o0 = {}, o1 = {};
  float mrow = -1e30f, lrow = 0.f;

  for (int kt = 0; kt < SEQ / 64; kt++) {
    bf16* sK = lKV[kt & 1][0];
    bf16* sV = lKV[kt & 1][1];
    *(uint4*)&sK[srow * LSTR + sch]        = kr0;
    *(uint4*)&sK[(32 + srow) * LSTR + sch] = kr1;
    *(uint4*)&sV[srow * LSTR + sch]        = vr0;
    *(uint4*)&sV[(32 + srow) * LSTR + sch] = vr1;
    __syncthreads();

    const int ktn = (kt + 1) & (SEQ / 64 - 1);
    kr0 = *(const uint4*)(kg + (size_t)ktn * 64 * HDIM);
    kr1 = *(const uint4*)(kg + (size_t)ktn * 64 * HDIM + 32 * HDIM);
    vr0 = *(const uint4*)(vg + ktn * 64);
    vr1 = *(const uint4*)(vg + ktn * 64 + 32 * SEQ);

    // S^T(t) = K Q^T
    f32x16 s0 = {}, s1 = {};
#pragma unroll
    for (int c = 0; c < 4; c++) {
      bf16x8 k0 = *(const bf16x8*)&sK[l31 * LSTR + c * 16 + h * 8];
      bf16x8 k1 = *(const bf16x8*)&sK[(32 + l31) * LSTR + c * 16 + h * 8];
      s0 = __builtin_amdgcn_mfma_f32_32x32x16_bf16(k0, qf[c], s0, 0, 0, 0);
      s1 = __builtin_amdgcn_mfma_f32_32x32x16_bf16(k1, qf[c], s1, 0, 0, 0);
    }

    // PV(t-1): P in pf regs, V(t-1) in the OTHER KV buffer.
    if (kt > 0) {
      const bf16* pV = lKV[(kt + 1) & 1][1];
#pragma unroll
      for (int c = 0; c < 4; c++) {
        bf16x8 v0 = *(const bf16x8*)&pV[l31 * LSTR + c * 16 + h * 8];
        bf16x8 v1 = *(const bf16x8*)&pV[(32 + l31) * LSTR + c * 16 + h * 8];
        o0 = __builtin_amdgcn_mfma_f32_32x32x16_bf16(v0, pf[c], o0, 0, 0, 0);
        o1 = __builtin_amdgcn_mfma_f32_32x32x16_bf16(v1, pf[c], o1, 0, 0, 0);
      }
    }

    // softmax(t)
    float mx = -1e30f;
#pragma unroll
    for (int r = 0; r < 16; r++) { mx = fmaxf(mx, s0[r]); mx = fmaxf(mx, s1[r]); }
    mx = fmaxf(mx, __shfl_xor(mx, 32, 64));
    const float nm = fmaxf(mrow, mx);
    const float alpha = EXP2F(mrow - nm);
    mrow = nm;

    float rs = 0.f;
#pragma unroll
    for (int r = 0; r < 16; r++) {
      const float p0 = EXP2F(s0[r] - nm);
      const float p1 = EXP2F(s1[r] - nm);
      s0[r] = p0; s1[r] = p1;
      rs += p0 + p1;
    }
    rs += __shfl_xor(rs, 32, 64);
    lrow = lrow * alpha + rs;

#pragma unroll
    for (int r = 0; r < 16; r++) { o0[r] *= alpha; o1[r] *= alpha; }

    // pack P(t) -> pf regs via half-exchange
#pragma unroll
    for (int g = 0; g < 2; g++) {
      const f32x16& sg = (g == 0) ? s0 : s1;
#pragma unroll
      for (int cp = 0; cp < 2; cp++) {
        bf16x4 pk0 = { (bf16)sg[8 * cp + 0], (bf16)sg[8 * cp + 1],
                       (bf16)sg[8 * cp + 2], (bf16)sg[8 * cp + 3] };   // q=2cp
        bf16x4 pk1 = { (bf16)sg[8 * cp + 4], (bf16)sg[8 * cp + 5],
                       (bf16)sg[8 * cp + 6], (bf16)sg[8 * cp + 7] };   // q=2cp+1
        uint2 w0 = *(uint2*)&pk0;
        uint2 w1 = *(uint2*)&pk1;
        unsigned send0 = h ? w0.x : w1.x;
        unsigned send1 = h ? w0.y : w1.y;
        unsigned recv0 = __shfl_xor(send0, 32, 64);
        unsigned recv1 = __shfl_xor(send1, 32, 64);
        union { unsigned u[4]; bf16x8 v; } f;
        f.u[0] = h ? recv0 : w0.x;
        f.u[1] = h ? recv1 : w0.y;
        f.u[2] = h ? w1.x : recv0;
        f.u[3] = h ? w1.y : recv1;
        pf[2 * g + cp] = f.v;
      }
    }
  }

  // drain: PV(31)
  {
    const bf16* pV = lKV[1][1];
#pragma unroll
    for (int c = 0; c < 4; c++) {
      bf16x8 v0 = *(const bf16x8*)&pV[l31 * LSTR + c * 16 + h * 8];
      bf16x8 v1 = *(const bf16x8*)&pV[(32 + l31) * LSTR + c * 16 + h * 8];
      o0 = __builtin_amdgcn_mfma_f32_32x32x16_bf16(v0, pf[c], o0, 0, 0, 0);
      o1 = __builtin_amdgcn_mfma_f32_32x32x16_bf16(v1, pf[c], o1, 0, 0, 0);
    }
  }

  const int b = bh >> 4, head = bh & 15;
  const float inv = 1.f / lrow;
  const size_t base = ((size_t)b * SEQ + qrow) * DIMD + head * HDIM;
#pragma unroll
  for (int g = 0; g < 4; g++) {
    bf16x4 oa = { (bf16)(o0[4*g] * inv), (bf16)(o0[4*g+1] * inv),
                  (bf16)(o0[4*g+2] * inv), (bf16)(o0[4*g+3] * inv) };
    bf16x4 ob = { (bf16)(o1[4*g] * inv), (bf16)(o1[4*g+1] * inv),
                  (bf16)(o1[4*g+2] * inv), (bf16)(o1[4*g+3] * inv) };
    *(bf16x4*)&Ob[base + g * 8 + h * 4]      = oa;
    *(bf16x4*)&Ob[base + 32 + g * 8 + h * 4] = ob;
  }
}

extern "C" void kernel_launch(void* const* d_in, const int* in_sizes, int n_in,
                              void* d_out, int out_size, void* d_ws, size_t ws_size,
                              hipStream_t stream) {
  const float* x      = (const float*)d_in[0];
  const float* w_qkv  = (const float*)d_in[1];
  const float* b_qkv  = (const float*)d_in[2];
  const float* w_proj = (const float*)d_in[3];
  const float* b_proj = (const float*)d_in[4];
  float* out = (float*)d_out;
  char* ws = (char*)d_ws;

  bf16* Qb = (bf16*)d_out;
  bf16* Kb = (bf16*)d_out + (size_t)MTOT * DIMD;
  bf16* xb     = (bf16*)(ws + OFF_XB);
  bf16* Ob     = (bf16*)(ws + OFF_OB);   // overlays xb (dead after QKV GEMM)
  bf16* Vt     = (bf16*)(ws + OFF_VT);
  bf16* wqkvb  = (bf16*)(ws + OFF_WQ);
  bf16* wprojb = (bf16*)(ws + OFF_WP);

  const int NCVT = (MTOT * DIMD / 4) + (3 * DIMD * DIMD / 4) + (DIMD * DIMD / 4);
  cvt3_kernel<<<NCVT / 256, 256, 0, stream>>>(x, w_qkv, w_proj, xb, wqkvb, wprojb);
  gemm_qkv<<<dim3(24, 32), 256, 0, stream>>>(xb, wqkvb, b_qkv, Qb, Kb, Vt);
  attn_kernel<<<BATCH * NHEAD * (SEQ / 128), 256, 0, stream>>>(Qb, Kb, Vt, Ob);
  gemm_proj<<<dim3(8, 64), 256, 0, stream>>>(Ob, wprojb, b_proj, out);
}